// Round 5
// baseline (586.110 us; speedup 1.0000x reference)
//
#include <hip/hip_runtime.h>
#include <hip/hip_bf16.h>
#include <cstddef>
#include <cstdint>

// B=16, DIM=256, H=W=80, C=64/branch, HEADS=8, DH=8, n=6400
typedef __attribute__((ext_vector_type(8))) short short8;
typedef __attribute__((ext_vector_type(4))) float f32x4;
typedef unsigned short ushortT;

// Workspace layout (float offsets):
static constexpr size_t OFF_Y    = 0;          // y fp32 [b][256][6400]
static constexpr size_t OFF_YHI  = 26214400;   // y hi bf16 [b][br][t][c]  (26.2M ushort)
static constexpr size_t OFF_YLO  = 39321600;   // y lo bf16 [b][br][t][c]
static constexpr size_t OFF_CTX  = 52428800;   // ctx [br*16+b][h][e][d] (32768)
static constexpr size_t OFF_QS   = 52461568;   // qs  [br*16+b][h][e]    (4096)
static constexpr size_t OFF_CTXN = 52465664;   // normalized ctx (32768)
static constexpr size_t OFF_WCF  = 52498432;   // Wc frags [16mt][8ks][64][8] bf16
static constexpr size_t OFF_WQF  = 52531200;   // wqkv frags [12rt][2ks][64][8] bf16
static constexpr size_t OFF_BC   = 52537344;   // bc [256]

__device__ inline ushortT f2bf(float f) {
    __hip_bfloat16 h = __float2bfloat16(f);
    return *reinterpret_cast<ushortT*>(&h);
}
__device__ inline float bf2f(ushortT u) {
    __hip_bfloat16 h = *reinterpret_cast<__hip_bfloat16*>(&u);
    return __bfloat162float(h);
}

// ---------------------------------------------------------------------------
// Pack wqkv into MFMA A-fragment order (single bf16).
__global__ void pack_wq(const float* __restrict__ wqkv, ushortT* __restrict__ wqf) {
    int idx = blockIdx.x * 256 + threadIdx.x;
    if (idx < 12288) {
        int i = idx & 7, ln = (idx >> 3) & 63, kk = idx >> 9;
        int rt = kk >> 1, ks = kk & 1;
        int row = rt * 16 + (ln & 15), col = ks * 32 + ((ln >> 4) & 3) * 8 + i;
        wqf[idx] = f2bf(wqkv[row * 64 + col]);
    }
}

// ---------------------------------------------------------------------------
// Fold wproj/scale/wf into combined weight as bf16 MFMA A-fragments + bias.
__global__ void combine_w(const float* __restrict__ wf, const float* __restrict__ wproj,
                          const float* __restrict__ bproj, const float* __restrict__ bf,
                          const float* __restrict__ scale,
                          ushortT* __restrict__ wcf, float* __restrict__ bc) {
    int o  = blockIdx.x;     // 256
    int cp = threadIdx.x;    // 64
    for (int i = 0; i < 4; i++) {
        float s = 0.f;
        for (int d = 0; d < 64; d++)
            s = fmaf(wf[o * 256 + i * 64 + d], wproj[d * 64 + cp], s);
        s *= scale[i];
        int col = i * 64 + cp;
        int mt = o >> 4, ks = col >> 5, ln = (o & 15) | (((col >> 3) & 3) << 4), ii = col & 7;
        wcf[((mt * 8 + ks) * 64 + ln) * 8 + ii] = f2bf(s);
    }
    if (cp == 0) {
        float s = bf[o];
        for (int i = 0; i < 4; i++) {
            float t = 0.f;
            for (int d = 0; d < 64; d++)
                t = fmaf(wf[o * 256 + i * 64 + d], bproj[d], t);
            s = fmaf(scale[i], t, s);
        }
        bc[o] = s;
    }
}

// ---------------------------------------------------------------------------
// Depthwise conv KxK + bias + residual + relu, vectorized float4.
template<int K>
__global__ __launch_bounds__(256) void dwconv_k(const float* __restrict__ x,
    const float* __restrict__ w, const float* __restrict__ bias,
    float* __restrict__ y, int br) {
    __shared__ float tile[88 * 88];
    int b = blockIdx.x >> 6, c = blockIdx.x & 63;
    int ch = br * 64 + c;
    const float* xp = x + ((size_t)b * 256 + ch) * 6400;
    for (int idx = threadIdx.x; idx < 88 * 22; idx += 256) {
        int r = idx / 22, c4 = idx - (idx / 22) * 22;
        int sy = r - 4;
        float4 v = make_float4(0.f, 0.f, 0.f, 0.f);
        if (sy >= 0 && sy < 80 && c4 >= 1 && c4 <= 20)
            v = *(const float4*)&xp[sy * 80 + (c4 - 1) * 4];
        *(float4*)&tile[r * 88 + c4 * 4] = v;
    }
    constexpr int R = (K - 1) / 2;
    float wr[K * K];
    #pragma unroll
    for (int q = 0; q < K * K; q++) wr[q] = w[c * K * K + q];
    float bv = bias[c];
    __syncthreads();
    float* yp = y + ((size_t)b * 256 + ch) * 6400;
    for (int p4 = threadIdx.x; p4 < 1600; p4 += 256) {
        int py = p4 / 20, px = (p4 - (p4 / 20) * 20) * 4;
        const float* tc = &tile[(py + 4) * 88 + px + 4];
        float4 rsd = *(const float4*)tc;
        float a0 = bv + rsd.x, a1 = bv + rsd.y, a2 = bv + rsd.z, a3 = bv + rsd.w;
        #pragma unroll
        for (int ky = 0; ky < K; ky++) {
            const float* trow = tc + (ky - R) * 88 - 4;   // aligned 12-float window
            float f[12];
            *(float4*)&f[0] = *(const float4*)&trow[0];
            *(float4*)&f[4] = *(const float4*)&trow[4];
            *(float4*)&f[8] = *(const float4*)&trow[8];
            #pragma unroll
            for (int kx = 0; kx < K; kx++) {
                float wv = wr[ky * K + kx];
                a0 = fmaf(wv, f[4 - R + kx + 0], a0);
                a1 = fmaf(wv, f[4 - R + kx + 1], a1);
                a2 = fmaf(wv, f[4 - R + kx + 2], a2);
                a3 = fmaf(wv, f[4 - R + kx + 3], a3);
            }
        }
        float4 o;
        o.x = fmaxf(a0, 0.f); o.y = fmaxf(a1, 0.f);
        o.z = fmaxf(a2, 0.f); o.w = fmaxf(a3, 0.f);
        *(float4*)&yp[py * 80 + px] = o;
    }
}

// ---------------------------------------------------------------------------
// k1: pack y->bf16 hi/lo frags (for k2), qs sums, k-softmax (in-register),
// ctx accumulation. No __syncthreads: per-wave LDS + lgkmcnt fences.
// grid (25, 16, 4), block 256 = 4 waves; wave owns 64 tokens.
__global__ __launch_bounds__(256, 4) void attn_kv(const float* __restrict__ y,
    const ushortT* __restrict__ wqf, ushortT* __restrict__ yhi,
    ushortT* __restrict__ ylo, float* __restrict__ ctx, float* __restrict__ qs) {
    __shared__ ushortT kv_s[4][32][136];
    int b = blockIdx.y, br = blockIdx.z;
    int w = threadIdx.x >> 6, lane = threadIdx.x & 63;
    int gp = lane >> 4, c15 = lane & 15;
    int t0 = blockIdx.x * 256 + w * 64;
    const float* yb = y + ((size_t)b * 256 + br * 64) * 6400;
    size_t pkb = (size_t)(b * 4 + br) * 409600;
    const short8* wfp = (const short8*)wqf;

    // build hi/lo frags for 64 tokens and store y_pk
    short8 byh[4][2], byl[4][2];
    #pragma unroll
    for (int tt = 0; tt < 4; tt++) {
        int t = t0 + tt * 16 + c15;
        #pragma unroll
        for (int ks = 0; ks < 2; ks++) {
            int c0 = ks * 32 + gp * 8;
            float v[8];
            #pragma unroll
            for (int i = 0; i < 8; i++) v[i] = yb[(size_t)(c0 + i) * 6400 + t];
            short8 hi, lo;
            #pragma unroll
            for (int i = 0; i < 8; i++) {
                ushortT hb = f2bf(v[i]);
                hi[i] = (short)hb;
                lo[i] = (short)f2bf(v[i] - bf2f(hb));
            }
            byh[tt][ks] = hi; byl[tt][ks] = lo;
            *(short8*)&yhi[pkb + (size_t)t * 64 + c0] = hi;
            *(short8*)&ylo[pkb + (size_t)t * 64 + c0] = lo;
        }
    }
    // q rows (rt 0..3): exp -> qsum regs
    float qsum[16];
    #pragma unroll
    for (int j = 0; j < 16; j++) qsum[j] = 0.f;
    #pragma unroll
    for (int rt = 0; rt < 4; rt++) {
        short8 a0 = wfp[(rt * 2 + 0) * 64 + lane];
        short8 a1 = wfp[(rt * 2 + 1) * 64 + lane];
        #pragma unroll
        for (int tt = 0; tt < 4; tt++) {
            f32x4 acc = {0.f, 0.f, 0.f, 0.f};
            acc = __builtin_amdgcn_mfma_f32_16x16x32_bf16(a0, byh[tt][0], acc, 0, 0, 0);
            acc = __builtin_amdgcn_mfma_f32_16x16x32_bf16(a1, byh[tt][1], acc, 0, 0, 0);
            acc = __builtin_amdgcn_mfma_f32_16x16x32_bf16(a0, byl[tt][0], acc, 0, 0, 0);
            acc = __builtin_amdgcn_mfma_f32_16x16x32_bf16(a1, byl[tt][1], acc, 0, 0, 0);
            #pragma unroll
            for (int q = 0; q < 4; q++) qsum[rt * 4 + q] += __expf(acc[q]);
        }
    }
    {
        float* qsg = qs + (size_t)(br * 16 + b) * 64;
        #pragma unroll
        for (int j = 0; j < 16; j++) {
            float v = qsum[j];
            v += __shfl_xor(v, 1); v += __shfl_xor(v, 2);
            v += __shfl_xor(v, 4); v += __shfl_xor(v, 8);
            if (c15 == 0) {
                int h = 2 * (j >> 2) + (gp >> 1);
                int e = (gp & 1) * 4 + (j & 3);
                atomicAdd(&qsg[h * 8 + e], v);
            }
        }
    }
    // k,v halves (32 tokens each): in-register softmax, ctx accumulation
    float cacc[8];
    #pragma unroll
    for (int d = 0; d < 8; d++) cacc[d] = 0.f;
    int h2 = lane >> 3, e2 = lane & 7;
    #pragma unroll
    for (int half = 0; half < 2; half++) {
        #pragma unroll
        for (int rt = 0; rt < 4; rt++) {        // k rows (global rt+4)
            short8 a0 = wfp[((rt + 4) * 2 + 0) * 64 + lane];
            short8 a1 = wfp[((rt + 4) * 2 + 1) * 64 + lane];
            int row0 = rt * 16 + gp * 4;
            #pragma unroll
            for (int tt2 = 0; tt2 < 2; tt2++) {
                int tt = half * 2 + tt2;
                f32x4 acc = {0.f, 0.f, 0.f, 0.f};
                acc = __builtin_amdgcn_mfma_f32_16x16x32_bf16(a0, byh[tt][0], acc, 0, 0, 0);
                acc = __builtin_amdgcn_mfma_f32_16x16x32_bf16(a1, byh[tt][1], acc, 0, 0, 0);
                acc = __builtin_amdgcn_mfma_f32_16x16x32_bf16(a0, byl[tt][0], acc, 0, 0, 0);
                acc = __builtin_amdgcn_mfma_f32_16x16x32_bf16(a1, byl[tt][1], acc, 0, 0, 0);
                float m = fmaxf(fmaxf(acc[0], acc[1]), fmaxf(acc[2], acc[3]));
                m = fmaxf(m, __shfl_xor(m, 16));
                float k0 = __expf(acc[0] - m), k1 = __expf(acc[1] - m);
                float k2v = __expf(acc[2] - m), k3 = __expf(acc[3] - m);
                float s = k0 + k1 + k2v + k3;
                s += __shfl_xor(s, 16);
                float inv = 1.f / s;
                uint2 pk;
                pk.x = (uint)f2bf(k0 * inv) | ((uint)f2bf(k1 * inv) << 16);
                pk.y = (uint)f2bf(k2v * inv) | ((uint)f2bf(k3 * inv) << 16);
                *(uint2*)&kv_s[w][tt2 * 16 + c15][row0] = pk;
            }
        }
        #pragma unroll
        for (int rt = 0; rt < 4; rt++) {        // v rows (global rt+8)
            short8 a0 = wfp[((rt + 8) * 2 + 0) * 64 + lane];
            short8 a1 = wfp[((rt + 8) * 2 + 1) * 64 + lane];
            int row0 = rt * 16 + gp * 4;
            #pragma unroll
            for (int tt2 = 0; tt2 < 2; tt2++) {
                int tt = half * 2 + tt2;
                f32x4 acc = {0.f, 0.f, 0.f, 0.f};
                acc = __builtin_amdgcn_mfma_f32_16x16x32_bf16(a0, byh[tt][0], acc, 0, 0, 0);
                acc = __builtin_amdgcn_mfma_f32_16x16x32_bf16(a1, byh[tt][1], acc, 0, 0, 0);
                acc = __builtin_amdgcn_mfma_f32_16x16x32_bf16(a0, byl[tt][0], acc, 0, 0, 0);
                acc = __builtin_amdgcn_mfma_f32_16x16x32_bf16(a1, byl[tt][1], acc, 0, 0, 0);
                uint2 pk;
                pk.x = (uint)f2bf(acc[0]) | ((uint)f2bf(acc[1]) << 16);
                pk.y = (uint)f2bf(acc[2]) | ((uint)f2bf(acc[3]) << 16);
                *(uint2*)&kv_s[w][tt2 * 16 + c15][64 + row0] = pk;
            }
        }
        asm volatile("s_waitcnt lgkmcnt(0)" ::: "memory");
        __builtin_amdgcn_sched_barrier(0);
        #pragma unroll 4
        for (int t = 0; t < 32; t++) {
            float kv = bf2f(kv_s[w][t][h2 * 8 + e2]);
            short8 v8 = *(short8*)&kv_s[w][t][64 + h2 * 8];
            #pragma unroll
            for (int d = 0; d < 8; d++)
                cacc[d] = fmaf(kv, bf2f((ushortT)v8[d]), cacc[d]);
        }
        asm volatile("s_waitcnt lgkmcnt(0)" ::: "memory");
        __builtin_amdgcn_sched_barrier(0);
    }
    float* cg = ctx + (size_t)(br * 16 + b) * 512 + lane * 8;
    #pragma unroll
    for (int d = 0; d < 8; d++) atomicAdd(&cg[d], cacc[d]);
}

// ---------------------------------------------------------------------------
// ctxn = ctx / qs
__global__ void norm_ctx(const float* __restrict__ ctx, const float* __restrict__ qs,
                         float* __restrict__ ctxn) {
    int g = blockIdx.x, p = threadIdx.x;
    ctxn[g * 512 + p] = ctx[g * 512 + p] / qs[g * 64 + (p >> 3)];
}

// ---------------------------------------------------------------------------
// k2: fused q-recompute (MFMA from y_pk) + exp + a-build (XOR-swizzled LDS)
// + Wc GEMM + bias + coalesced out stores.
// grid (50, 16), block 1024 = 16 waves. g-tile = 16 -> 128 tokens, 128 positions.
__global__ __launch_bounds__(1024) void final_out(
    const ushortT* __restrict__ yhi, const ushortT* __restrict__ ylo,
    const ushortT* __restrict__ wqf, const ushortT* __restrict__ wcf,
    const float* __restrict__ ctxn, const float* __restrict__ bc,
    float* __restrict__ out) {
    __shared__ ushortT a_hi[128 * 264];
    __shared__ ushortT a_lo[128 * 264];
    int b = blockIdx.y;
    int G0 = blockIdx.x * 16;
    int tid = threadIdx.x;
    int w = tid >> 6, lane = tid & 63, gp = lane >> 4, c15 = lane & 15;
    int t0 = G0 * 8;

    // ---- Phase A: wave w -> (mt = w&3, nt in {2*(w>>2), +1})
    int mt = w & 3, ntp = w >> 2;
    int hA = mt * 2 + (gp >> 1);
    int eb = (gp & 1) * 4;
    const short8* wfp = (const short8*)wqf;
    short8 a0 = wfp[(mt * 2 + 0) * 64 + lane];
    short8 a1 = wfp[(mt * 2 + 1) * 64 + lane];
    for (int br = 0; br < 4; br++) {
        const ushortT* yh = yhi + ((size_t)(b * 4 + br) * 6400 + t0) * 64;
        const ushortT* yl = ylo + ((size_t)(b * 4 + br) * 6400 + t0) * 64;
        const float* cx = ctxn + ((size_t)(br * 16 + b) * 8 + hA) * 64 + eb * 8;
        float cxr[32];
        #pragma unroll
        for (int p = 0; p < 8; p++) {
            float4 v4 = *(const float4*)&cx[p * 4];
            cxr[p * 4 + 0] = v4.x; cxr[p * 4 + 1] = v4.y;
            cxr[p * 4 + 2] = v4.z; cxr[p * 4 + 3] = v4.w;
        }
        #pragma unroll
        for (int ii = 0; ii < 2; ii++) {
            int nt = ntp * 2 + ii;
            int tl = nt * 16 + c15;
            short8 bh0 = *(const short8*)&yh[(size_t)tl * 64 + gp * 8];
            short8 bh1 = *(const short8*)&yh[(size_t)tl * 64 + 32 + gp * 8];
            short8 bl0 = *(const short8*)&yl[(size_t)tl * 64 + gp * 8];
            short8 bl1 = *(const short8*)&yl[(size_t)tl * 64 + 32 + gp * 8];
            f32x4 acc = {0.f, 0.f, 0.f, 0.f};
            acc = __builtin_amdgcn_mfma_f32_16x16x32_bf16(a0, bh0, acc, 0, 0, 0);
            acc = __builtin_amdgcn_mfma_f32_16x16x32_bf16(a1, bh1, acc, 0, 0, 0);
            acc = __builtin_amdgcn_mfma_f32_16x16x32_bf16(a0, bl0, acc, 0, 0, 0);
            acc = __builtin_amdgcn_mfma_f32_16x16x32_bf16(a1, bl1, acc, 0, 0, 0);
            float qe0 = __expf(acc[0]), qe1 = __expf(acc[1]);
            float qe2 = __expf(acc[2]), qe3 = __expf(acc[3]);
            int gl = tl >> 3, s = tl & 7;
            int j = hA * 16 + gl;
            short8 hi8, lo8;
            #pragma unroll
            for (int d = 0; d < 8; d++) {
                float part = qe0 * cxr[d] + qe1 * cxr[8 + d]
                           + qe2 * cxr[16 + d] + qe3 * cxr[24 + d];
                part += __shfl_xor(part, 16);
                ushortT hb = f2bf(part);
                hi8[d] = (short)hb;
                lo8[d] = (short)f2bf(part - bf2f(hb));
            }
            if ((gp & 1) == 0) {
                int cs = ((br * 8 + s) ^ (j & 7)) * 8;
                *(short8*)&a_hi[j * 264 + cs] = hi8;
                *(short8*)&a_lo[j * 264 + cs] = lo8;
            }
        }
    }
    __syncthreads();
    // ---- Phase B: wave w -> (mtq = w&3 -> mt2 = mtq*4+mi; ntp2 = w>>2 -> nt2 = ntp2*2+ni)
    int mtq = w & 3, ntp2 = w >> 2;
    const short8* wc8 = (const short8*)wcf;
    f32x4 acc2[4][2];
    #pragma unroll
    for (int mi = 0; mi < 4; mi++)
        #pragma unroll
        for (int ni = 0; ni < 2; ni++) acc2[mi][ni] = {0.f, 0.f, 0.f, 0.f};
    #pragma unroll 2
    for (int ks = 0; ks < 8; ks++) {
        short8 aw[4];
        #pragma unroll
        for (int mi = 0; mi < 4; mi++)
            aw[mi] = wc8[(size_t)((mtq * 4 + mi) * 8 + ks) * 64 + lane];
        short8 bh[2], bl[2];
        #pragma unroll
        for (int ni = 0; ni < 2; ni++) {
            int j = (ntp2 * 2 + ni) * 16 + c15;
            int cs = ((ks * 4 + gp) ^ (j & 7)) * 8;
            bh[ni] = *(const short8*)&a_hi[j * 264 + cs];
            bl[ni] = *(const short8*)&a_lo[j * 264 + cs];
        }
        #pragma unroll
        for (int mi = 0; mi < 4; mi++)
            #pragma unroll
            for (int ni = 0; ni < 2; ni++) {
                acc2[mi][ni] = __builtin_amdgcn_mfma_f32_16x16x32_bf16(aw[mi], bh[ni], acc2[mi][ni], 0, 0, 0);
                acc2[mi][ni] = __builtin_amdgcn_mfma_f32_16x16x32_bf16(aw[mi], bl[ni], acc2[mi][ni], 0, 0, 0);
            }
    }
    #pragma unroll
    for (int mi = 0; mi < 4; mi++) {
        int o = (mtq * 4 + mi) * 16 + gp * 4;
        float b0 = bc[o], b1 = bc[o + 1], b2 = bc[o + 2], b3 = bc[o + 3];
        #pragma unroll
        for (int ni = 0; ni < 2; ni++) {
            int j = (ntp2 * 2 + ni) * 16 + c15;
            int np = (j >> 4) * 800 + G0 + (j & 15);
            float* op = out + ((size_t)b * 256 + o) * 6400 + np;
            op[0]          = acc2[mi][ni][0] + b0;
            op[6400]       = acc2[mi][ni][1] + b1;
            op[2 * 6400]   = acc2[mi][ni][2] + b2;
            op[3 * 6400]   = acc2[mi][ni][3] + b3;
        }
    }
}

// ---------------------------------------------------------------------------
extern "C" void kernel_launch(void* const* d_in, const int* in_sizes, int n_in,
                              void* d_out, int out_size, void* d_ws, size_t ws_size,
                              hipStream_t stream) {
    const float* x     = (const float*)d_in[0];
    const float* w3    = (const float*)d_in[1];
    const float* b3    = (const float*)d_in[2];
    const float* w5    = (const float*)d_in[3];
    const float* b5    = (const float*)d_in[4];
    const float* w7    = (const float*)d_in[5];
    const float* b7    = (const float*)d_in[6];
    const float* w9    = (const float*)d_in[7];
    const float* b9    = (const float*)d_in[8];
    const float* wqkv  = (const float*)d_in[9];
    const float* wproj = (const float*)d_in[10];
    const float* bproj = (const float*)d_in[11];
    const float* wf    = (const float*)d_in[12];
    const float* bf    = (const float*)d_in[13];
    const float* scale = (const float*)d_in[14];
    float* out = (float*)d_out;
    float* ws  = (float*)d_ws;

    hipMemsetAsync(ws + OFF_CTX, 0, (32768 + 4096) * sizeof(float), stream);

    pack_wq<<<48, 256, 0, stream>>>(wqkv, (ushortT*)(ws + OFF_WQF));
    combine_w<<<256, 64, 0, stream>>>(wf, wproj, bproj, bf, scale,
                                      (ushortT*)(ws + OFF_WCF), ws + OFF_BC);

    dwconv_k<3><<<1024, 256, 0, stream>>>(x, w3, b3, ws + OFF_Y, 0);
    dwconv_k<5><<<1024, 256, 0, stream>>>(x, w5, b5, ws + OFF_Y, 1);
    dwconv_k<7><<<1024, 256, 0, stream>>>(x, w7, b7, ws + OFF_Y, 2);
    dwconv_k<9><<<1024, 256, 0, stream>>>(x, w9, b9, ws + OFF_Y, 3);

    attn_kv<<<dim3(25, 16, 4), 256, 0, stream>>>(ws + OFF_Y,
        (const ushortT*)(ws + OFF_WQF), (ushortT*)(ws + OFF_YHI),
        (ushortT*)(ws + OFF_YLO), ws + OFF_CTX, ws + OFF_QS);

    norm_ctx<<<64, 512, 0, stream>>>(ws + OFF_CTX, ws + OFF_QS, ws + OFF_CTXN);

    final_out<<<dim3(50, 16), 1024, 0, stream>>>(
        (const ushortT*)(ws + OFF_YHI), (const ushortT*)(ws + OFF_YLO),
        (const ushortT*)(ws + OFF_WQF), (const ushortT*)(ws + OFF_WCF),
        ws + OFF_CTXN, ws + OFF_BC, out);
}